// Round 17
// baseline (74.314 us; speedup 1.0000x reference)
//
#include <hip/hip_runtime.h>

// Problem constants (from reference)
constexpr int N = 2;
constexpr int C = 20;
constexpr int H = 64;
constexpr int W = 2048;          // power of two -> wrap via & (W-1)
constexpr int HW = H * W;        // 131072 = 2^17

// ---------------------------------------------------------------------------
// Kernel 1: fold mask into softmax and transpose NCHW -> NHWC.
// smt[site][c], 20 contiguous floats (80 B) per site, site = n*HW + h*W + w.
// Pure streaming: 21 MB read (coalesced) + 2 MB mask + 21 MB write.
// ---------------------------------------------------------------------------
__global__ __launch_bounds__(256)
void transpose_kernel(const float* __restrict__ softmax,
                      const int* __restrict__ mask,
                      float* __restrict__ smt) {
    const int idx = blockIdx.x * 256 + threadIdx.x;   // flat site, 0..262143
    const int n   = idx >> 17;                        // / HW
    const int hw  = idx & (HW - 1);

    const float* sp = softmax + (size_t)n * C * HW + hw;
    const float  m  = (float)mask[idx];

    float v[20];
    #pragma unroll
    for (int c = 0; c < 20; ++c)
        v[c] = sp[(size_t)c * HW] * m;     // 20 coalesced strided loads

    float* o = smt + (size_t)idx * 20;
    #pragma unroll
    for (int q = 0; q < 5; ++q) {
        float4 f;
        f.x = v[4 * q];     f.y = v[4 * q + 1];
        f.z = v[4 * q + 2]; f.w = v[4 * q + 3];
        *(float4*)(o + 4 * q) = f;
    }
}

// ---------------------------------------------------------------------------
// Kernel 2: one thread per site. 25 gaussian weights in registers; per tap,
// 5 contiguous float4 loads deliver all 20 classes; acc[20] in registers.
// No LDS, no barriers, no per-class staging. Per-wave tap footprint
// 5 rows x 68 cols x 80 B = 27 KB -> L1-resident (4.7x overlap reuse).
// ---------------------------------------------------------------------------
__global__ __launch_bounds__(256, 4)   // ~90 VGPR -> 4 blocks/CU, 16 waves/CU
void gather_kernel(const float* __restrict__ xyz,
                   const float* __restrict__ smt,
                   float* __restrict__ out) {
    const int t = threadIdx.x;

    // XCD swizzle (R6-measured-good at 1024 blocks): XCD (bid%8) owns 128
    // consecutive works = 16 contiguous (n*64+h) rows on one L2.
    const int bid  = blockIdx.x;
    const int work = (bid & 7) * 128 + (bid >> 3);   // bijective over [0,1024)
    const int nh   = work >> 3;
    const int bw   = work & 7;
    const int n    = nh >> 6;
    const int h    = nh & 63;
    const int oc   = bw * 256 + t;       // this thread's output col
    const int p    = oc & 1;             // col parity (xyz float2 alignment)

    const float* xb = xyz + (size_t)(n * 3 + 0) * HW;
    const float* yb = xyz + (size_t)(n * 3 + 1) * HW;
    const float* zb = xyz + (size_t)(n * 3 + 2) * HW;

    int  rowoff[5];                      // clipped row * W (within image n)
    bool hv[5];
    #pragma unroll
    for (int r = 0; r < 5; ++r) {
        int hh = h - 2 + r;
        hv[r] = (unsigned)hh < (unsigned)H;
        rowoff[r] = min(max(hh, 0), H - 1) * W;
    }

    // ---- Weight phase: 6-slot aligned float2 loads, slot k = col oc-2-p+k.
    //      Validity folds in via d2=1e30 -> exp -> 0. Mask already in smt.
    const float cx = xb[h * W + oc];
    const float cy = yb[h * W + oc];
    const float cz = zb[h * W + oc];

    const int sc0 = (oc - 2 - p) & (W - 1);   // even -> 8B aligned
    const int sc1 = (oc     - p) & (W - 1);
    const int sc2 = (oc + 2 - p) & (W - 1);

    float wgt[5][5];
    #pragma unroll
    for (int r = 0; r < 5; ++r) {
        float2 x0 = *(const float2*)(xb + rowoff[r] + sc0);
        float2 x1 = *(const float2*)(xb + rowoff[r] + sc1);
        float2 x2 = *(const float2*)(xb + rowoff[r] + sc2);
        float2 y0 = *(const float2*)(yb + rowoff[r] + sc0);
        float2 y1 = *(const float2*)(yb + rowoff[r] + sc1);
        float2 y2 = *(const float2*)(yb + rowoff[r] + sc2);
        float2 z0 = *(const float2*)(zb + rowoff[r] + sc0);
        float2 z1 = *(const float2*)(zb + rowoff[r] + sc1);
        float2 z2 = *(const float2*)(zb + rowoff[r] + sc2);

        const float xv[6] = {x0.x, x0.y, x1.x, x1.y, x2.x, x2.y};
        const float yv[6] = {y0.x, y0.y, y1.x, y1.y, y2.x, y2.y};
        const float zv[6] = {z0.x, z0.y, z1.x, z1.y, z2.x, z2.y};

        float w6[6];
        #pragma unroll
        for (int k = 0; k < 6; ++k) {
            float dx = xv[k] - cx, dy = yv[k] - cy, dz = zv[k] - cz;
            float d2 = dx * dx + dy * dy + dz * dz;
            d2 = hv[r] ? d2 : 1e30f;              // invalid row -> exp -> 0
            w6[k] = __expf(-0.5f * d2);           // GAUSS_DEN = 2*sigma^2 = 2
        }
        // tap j sits at slot j+p; both branches static-indexed (predicated)
        #pragma unroll
        for (int j = 0; j < 5; ++j)
            wgt[r][j] = p ? w6[j + 1] : w6[j];
    }

    // ---- Tap loop: 25 taps x (5 float4 loads + 20 FMA). All reg-resident.
    int rowb[5], colb[5];
    #pragma unroll
    for (int r = 0; r < 5; ++r) rowb[r] = (n * HW + rowoff[r]) * 20;
    #pragma unroll
    for (int j = 0; j < 5; ++j) colb[j] = (((oc + j - 2) & (W - 1))) * 20;

    float acc[20];
    #pragma unroll
    for (int c = 0; c < 20; ++c) acc[c] = 0.0f;

    #pragma unroll
    for (int r = 0; r < 5; ++r) {
        #pragma unroll
        for (int j = 0; j < 5; ++j) {
            const float* pp = smt + (size_t)(rowb[r] + colb[j]);
            const float  wv = wgt[r][j];
            float4 a0 = *(const float4*)(pp);
            float4 a1 = *(const float4*)(pp + 4);
            float4 a2 = *(const float4*)(pp + 8);
            float4 a3 = *(const float4*)(pp + 12);
            float4 a4 = *(const float4*)(pp + 16);
            acc[ 0] = fmaf(wv, a0.x, acc[ 0]);  acc[ 1] = fmaf(wv, a0.y, acc[ 1]);
            acc[ 2] = fmaf(wv, a0.z, acc[ 2]);  acc[ 3] = fmaf(wv, a0.w, acc[ 3]);
            acc[ 4] = fmaf(wv, a1.x, acc[ 4]);  acc[ 5] = fmaf(wv, a1.y, acc[ 5]);
            acc[ 6] = fmaf(wv, a1.z, acc[ 6]);  acc[ 7] = fmaf(wv, a1.w, acc[ 7]);
            acc[ 8] = fmaf(wv, a2.x, acc[ 8]);  acc[ 9] = fmaf(wv, a2.y, acc[ 9]);
            acc[10] = fmaf(wv, a2.z, acc[10]);  acc[11] = fmaf(wv, a2.w, acc[11]);
            acc[12] = fmaf(wv, a3.x, acc[12]);  acc[13] = fmaf(wv, a3.y, acc[13]);
            acc[14] = fmaf(wv, a3.z, acc[14]);  acc[15] = fmaf(wv, a3.w, acc[15]);
            acc[16] = fmaf(wv, a4.x, acc[16]);  acc[17] = fmaf(wv, a4.y, acc[17]);
            acc[18] = fmaf(wv, a4.z, acc[18]);  acc[19] = fmaf(wv, a4.w, acc[19]);
        }
    }

    // ---- Epilogue: 20 coalesced scalar stores (NCHW output) ----
    float* ob = out + (size_t)n * C * HW + (size_t)h * W + oc;
    #pragma unroll
    for (int c = 0; c < 20; ++c)
        ob[(size_t)c * HW] = acc[c];
}

extern "C" void kernel_launch(void* const* d_in, const int* in_sizes, int n_in,
                              void* d_out, int out_size, void* d_ws, size_t ws_size,
                              hipStream_t stream) {
    const float* xyz     = (const float*)d_in[0];
    const float* softmax = (const float*)d_in[1];
    const int*   mask    = (const int*)d_in[2];
    float*       out     = (float*)d_out;
    float*       smt     = (float*)d_ws;    // 262144 sites x 20 f = 21 MB

    const int sites = N * H * W;            // 262144
    transpose_kernel<<<sites / 256, 256, 0, stream>>>(softmax, mask, smt);

    const int grid = N * H * (W / 256);     // 1024 blocks
    gather_kernel<<<grid, 256, 0, stream>>>(xyz, smt, out);
}